// Round 2
// 525.837 us; speedup vs baseline: 1.0105x; 1.0105x over previous
//
#include <hip/hip_runtime.h>
#include <stdint.h>

#define BB 2
#define SS 2048
#define DD 1024
#define HH 8
#define HD 128
#define TOPK 32
#define ROWS (BB*HH*SS)   // 32768
#define BH 16

typedef float f32x4 __attribute__((ext_vector_type(4)));
typedef _Float16 f16x8 __attribute__((ext_vector_type(8)));
typedef _Float16 f16x4 __attribute__((ext_vector_type(4)));

__device__ __forceinline__ void gload_lds16(const _Float16* g, _Float16* l) {
    __builtin_amdgcn_global_load_lds(
        (const __attribute__((address_space(1))) void*)g,
        (__attribute__((address_space(3))) void*)l, 16, 0, 0);
}

// ---------------------------------------------------------------- K0: fp16 preconvert
// q,k,v [B,S,D] fp32 -> head-major [bh][s][128] fp16. Same RTN cast as the old
// in-kernel staging, so stats math is bit-compatible with the verified version.
__global__ __launch_bounds__(256) void cvt_kernel(const float* __restrict__ q,
                                                  const float* __restrict__ k,
                                                  const float* __restrict__ v,
                                                  _Float16* __restrict__ q16,
                                                  _Float16* __restrict__ k16,
                                                  _Float16* __restrict__ v16) {
    const int row = blockIdx.x;              // b*S + s
    const int b = row >> 11, s = row & 2047;
    const int t = threadIdx.x;
    const int h = t >> 5, d4 = (t & 31) * 4;
    const size_t src = (size_t)row * DD + t * 4;
    const size_t dst = ((size_t)(b * HH + h) * SS + s) * HD + d4;
    float4 f;
    f = *(const float4*)(q + src);
    *(f16x4*)(q16 + dst) = (f16x4){(_Float16)f.x,(_Float16)f.y,(_Float16)f.z,(_Float16)f.w};
    f = *(const float4*)(k + src);
    *(f16x4*)(k16 + dst) = (f16x4){(_Float16)f.x,(_Float16)f.y,(_Float16)f.z,(_Float16)f.w};
    f = *(const float4*)(v + src);
    *(f16x4*)(v16 + dst) = (f16x4){(_Float16)f.x,(_Float16)f.y,(_Float16)f.z,(_Float16)f.w};
}

// ---------------------------------------------------------------- K1: top-32
// (unchanged — verified; ~memory-floor on the 268 MB aw stream)
__global__ __launch_bounds__(256) void topk_kernel(const float* __restrict__ aw,
                                                   int* __restrict__ idx_out) {
    const int row = blockIdx.x;
    const float* p = aw + (size_t)row * SS;
    const int t = threadIdx.x;
    float4 v0 = *(const float4*)(p + 4 * t);
    float4 v1 = *(const float4*)(p + 1024 + 4 * t);
    float vals[8] = {v0.x, v0.y, v0.z, v0.w, v1.x, v1.y, v1.z, v1.w};
    unsigned long long key[8];
#pragma unroll
    for (int i = 0; i < 8; i++) {
        int e = (i < 4) ? (4 * t + i) : (1024 + 4 * t + (i - 4));
        unsigned u = __float_as_uint(vals[i]);
        unsigned sk = (u & 0x80000000u) ? ~u : (u | 0x80000000u);
        key[i] = ((unsigned long long)sk << 11) | (unsigned)(2047 - e);
    }
    __shared__ int s_cnt;
    __shared__ int s_red[4];
    __shared__ unsigned long long s_cand[256];
    const int lane = t & 63, wv = t >> 6;

    unsigned thr0 = __float_as_uint(1.76f) | 0x80000000u;
    unsigned long long T = ((unsigned long long)thr0 << 11) | 2047ull;

    if (t == 0) s_cnt = 0;
    __syncthreads();
#pragma unroll
    for (int i = 0; i < 8; i++) {
        if (key[i] > T) {
            int pos = atomicAdd(&s_cnt, 1);
            if (pos < 256) s_cand[pos] = key[i];
        }
    }
    __syncthreads();

    if (s_cnt < TOPK || s_cnt > 256) {
        unsigned long long lo = 0, hi = ~0ull;
        if (s_cnt > 256) lo = T; else hi = T;
        T = lo + ((hi - lo) >> 1);
        for (int it = 0; it < 40; ++it) {
            int c = 0;
#pragma unroll
            for (int i = 0; i < 8; i++) c += (key[i] > T) ? 1 : 0;
            for (int off = 32; off; off >>= 1) c += __shfl_down(c, off, 64);
            if (lane == 0) s_red[wv] = c;
            __syncthreads();
            int tot = s_red[0] + s_red[1] + s_red[2] + s_red[3];
            if (tot >= TOPK && tot <= 256) break;
            if (tot > 256) lo = T; else hi = T;
            T = lo + ((hi - lo) >> 1);
            __syncthreads();
        }
        if (t == 0) s_cnt = 0;
        __syncthreads();
#pragma unroll
        for (int i = 0; i < 8; i++) {
            if (key[i] > T) {
                int pos = atomicAdd(&s_cnt, 1);
                if (pos < 256) s_cand[pos] = key[i];
            }
        }
        __syncthreads();
    }

    const int C = s_cnt < 256 ? s_cnt : 256;
    if (t < C) {
        unsigned long long mk = s_cand[t];
        int rank = 0;
        for (int j = 0; j < C; ++j)
            rank += (s_cand[j] > mk) ? 1 : 0;
        if (rank < TOPK)
            idx_out[(size_t)row * TOPK + rank] = 2047 - (int)(mk & 2047ull);
    }
}

// ------------------------------------------------------- K2: softmax stats
// Q fragments global->register (no LDS); K fp16 staged via global_load_lds
// dwordx4 into linear LDS with a both-sides XOR-chunk swizzle (involution
// chunk ^= row&7 baked into the per-lane GLOBAL source address; LDS dest
// stays linear per rule 21). Double-buffered 64-row K tiles, prefetch-
// before-compute, 1 barrier/tile. Split-K x4; XCD-pair swizzle: XCD x
// serves only bh {2x,2x+1} (k16 slice 1 MB -> re-reads L2-resident).
__global__ __launch_bounds__(256) void stats_kernel(const _Float16* __restrict__ q16,
                                                    const _Float16* __restrict__ k16,
                                                    float* __restrict__ ws_m,
                                                    float* __restrict__ ws_l) {
    __shared__ __align__(16) _Float16 Ks[2][64 * 128];   // 2 x 16 KB
    const int xcd = blockIdx.x & 7;
    const int r = blockIdx.x >> 3;
    const int bh = xcd * 2 + (r & 1);
    const int rr = r >> 1;
    const int qt = rr & 15;
    const int quarter = rr >> 4;          // 0..3: 512 keys each
    const int t = threadIdx.x;
    const int wv = t >> 6, lane = t & 63;
    const int l16 = lane & 15, quad = lane >> 4;

    // --- Q fragments straight into registers
    const _Float16* qb = q16 + ((size_t)bh * SS + qt * 128 + wv * 32 + l16) * HD;
    f16x8 af[2][4];
#pragma unroll
    for (int a = 0; a < 2; a++)
#pragma unroll
        for (int ks = 0; ks < 4; ks++)
            af[a][ks] = *(const f16x8*)(qb + a * 16 * HD + ks * 32 + quad * 8);

    // --- per-lane staging source offsets (halves) with inverse swizzle baked in.
    // call i covers LDS rows wv*16+i*4 .. +3; lane l -> row += l>>4, chunk cc'=l&15.
    // source chunk = cc' ^ ((i*4 + (l>>4)) & 7) == cc' ^ (row & 7)
    const int lr = lane >> 4, lc = lane & 15;
    int srco[4];
#pragma unroll
    for (int i = 0; i < 4; i++) {
        int x = ((i & 1) * 4) + lr;
        srco[i] = (wv * 16 + i * 4 + lr) * HD + ((lc ^ x) * 8);
    }
    const _Float16* kb = k16 + (size_t)bh * SS * HD;

    // precompute swizzled read chunk offsets (halves) per ks
    int rdoff[4];
#pragma unroll
    for (int ks = 0; ks < 4; ks++)
        rdoff[ks] = (((ks * 4 + quad) ^ (l16 & 7)) * 8);

    float mrun[2][4], lrun[2][4];
#pragma unroll
    for (int a = 0; a < 2; a++)
#pragma unroll
        for (int r2 = 0; r2 < 4; r2++) { mrun[a][r2] = -INFINITY; lrun[a][r2] = 0.f; }

    // prologue: stage tile 0
    {
        const _Float16* src = kb + (size_t)(quarter * 8) * 64 * HD;
#pragma unroll
        for (int i = 0; i < 4; i++)
            gload_lds16(src + srco[i], &Ks[0][(wv * 4 + i) * 512]);
    }
    __syncthreads();   // compiler drains vmcnt(0) before barrier

    int cur = 0;
    for (int tt = 0; tt < 8; ++tt) {
        if (tt < 7) {   // prefetch next tile into the other buffer
            const _Float16* src = kb + (size_t)(quarter * 8 + tt + 1) * 64 * HD;
#pragma unroll
            for (int i = 0; i < 4; i++)
                gload_lds16(src + srco[i], &Ks[cur ^ 1][(wv * 4 + i) * 512]);
        }
        f32x4 acc[2][4];
#pragma unroll
        for (int a = 0; a < 2; a++)
#pragma unroll
            for (int n = 0; n < 4; n++) acc[a][n] = (f32x4){0.f, 0.f, 0.f, 0.f};
#pragma unroll
        for (int ks = 0; ks < 4; ++ks) {
            f16x8 bfr[4];
#pragma unroll
            for (int n = 0; n < 4; n++)
                bfr[n] = *(const f16x8*)&Ks[cur][(n * 16 + l16) * HD + rdoff[ks]];
#pragma unroll
            for (int a = 0; a < 2; a++)
#pragma unroll
                for (int n = 0; n < 4; n++)
                    acc[a][n] = __builtin_amdgcn_mfma_f32_16x16x32_f16(af[a][ks], bfr[n], acc[a][n], 0, 0, 0);
        }
        // online max / sumexp per row (row = wv*32 + a*16 + quad*4 + r2)
#pragma unroll
        for (int a = 0; a < 2; a++) {
#pragma unroll
            for (int r2 = 0; r2 < 4; r2++) {
                float tm = fmaxf(fmaxf(acc[a][0][r2], acc[a][1][r2]),
                                 fmaxf(acc[a][2][r2], acc[a][3][r2]));
#pragma unroll
                for (int off = 1; off < 16; off <<= 1) tm = fmaxf(tm, __shfl_xor(tm, off, 64));
                float tl = 0.f;
#pragma unroll
                for (int n = 0; n < 4; n++) tl += __expf(acc[a][n][r2] - tm);
#pragma unroll
                for (int off = 1; off < 16; off <<= 1) tl += __shfl_xor(tl, off, 64);
                float mo = mrun[a][r2];
                float mn = fmaxf(mo, tm);
                lrun[a][r2] = lrun[a][r2] * __expf(mo - mn) + tl * __expf(tm - mn);
                mrun[a][r2] = mn;
            }
        }
        __syncthreads();   // next tile staged + everyone done with Ks[cur]
        cur ^= 1;
    }

    if (l16 == 0) {
#pragma unroll
        for (int a = 0; a < 2; a++)
#pragma unroll
            for (int r2 = 0; r2 < 4; r2++) {
                int rrow = qt * 128 + wv * 32 + a * 16 + quad * 4 + r2;
                size_t g = (size_t)quarter * ROWS + (size_t)bh * SS + rrow;
                ws_m[g] = mrun[a][r2];
                ws_l[g] = lrun[a][r2];
            }
    }
}

// --------------------------------------------- K2b: gather scores + PV
// Scores stay fp32 (accuracy); PV gathers fp16 v16 at float4 granularity
// (8 loads/thread instead of 32). Per-XCD working set: 2x k fp32 (2 MB)
// + 2x v16 (1 MB) = 3 MB < 4 MB L2.
__global__ __launch_bounds__(128) void attnout_kernel(const float* __restrict__ q,
                                                      const float* __restrict__ k,
                                                      const _Float16* __restrict__ v16,
                                                      const int* __restrict__ idx_ws,
                                                      const float* __restrict__ ws_m,
                                                      const float* __restrict__ ws_l,
                                                      float* __restrict__ out) {
    const int bh = blockIdx.x & 15;
    const int s = blockIdx.x >> 4;
    const int R = (bh << 11) | s;
    const int b = bh >> 3, h = bh & 7;
    const int t = threadIdx.x;
    __shared__ float q_l[128];
    __shared__ int idx_l[32];
    __shared__ float e_l[32];
    __shared__ float w_l[32];
    __shared__ __align__(16) float s_pv[4][128];
    const float* qrow = q + ((size_t)(b * SS + s) * DD + h * HD);
    q_l[t] = qrow[t];
    if (t < 32) idx_l[t] = idx_ws[(size_t)R * TOPK + t];
    __syncthreads();
    // merge 4 split-K partial stats
    float m = ws_m[R];
    m = fmaxf(m, ws_m[(size_t)ROWS + R]);
    m = fmaxf(m, ws_m[2 * (size_t)ROWS + R]);
    m = fmaxf(m, ws_m[3 * (size_t)ROWS + R]);
    float Z = 0.f;
#pragma unroll
    for (int qr = 0; qr < 4; ++qr)
        Z += ws_l[(size_t)qr * ROWS + R] * __expf(ws_m[(size_t)qr * ROWS + R] - m);

    const int l32 = t & 31, g = t >> 5;   // 4 groups of 32 lanes
    float4 q4 = *(const float4*)&q_l[l32 * 4];
    const float* kb = k + ((size_t)b * SS * DD + h * HD);
#pragma unroll
    for (int p = 0; p < 8; ++p) {
        int i = p * 4 + g;
        int ki = idx_l[i];
        float4 kv = *(const float4*)(kb + (size_t)ki * DD + l32 * 4);
        float d = q4.x * kv.x + q4.y * kv.y + q4.z * kv.z + q4.w * kv.w;
#pragma unroll
        for (int off = 1; off < 32; off <<= 1) d += __shfl_xor(d, off, 64);
        if (l32 == 0) e_l[i] = __expf(d - m);
    }
    __syncthreads();
    if (t < 32) {
        float e = e_l[t];
        float ssum = e;
#pragma unroll
        for (int off = 1; off < 32; off <<= 1) ssum += __shfl_xor(ssum, off, 64);
        float den = ssum + 1e-5f * Z;     // = S_sel + eps*Z (exact renorm algebra)
        w_l[t] = e / den;
    }
    __syncthreads();
    const _Float16* vb = v16 + (size_t)bh * SS * HD;
    float a0 = 0.f, a1 = 0.f, a2 = 0.f, a3 = 0.f;
#pragma unroll
    for (int p = 0; p < 8; ++p) {
        int i = p * 4 + g;
        f16x4 hv = *(const f16x4*)(vb + (size_t)idx_l[i] * HD + l32 * 4);
        float w = w_l[i];
        a0 += w * (float)hv[0];
        a1 += w * (float)hv[1];
        a2 += w * (float)hv[2];
        a3 += w * (float)hv[3];
    }
    *(float4*)&s_pv[g][l32 * 4] = make_float4(a0, a1, a2, a3);
    __syncthreads();
    out[((size_t)(b * SS + s) * DD) + h * HD + t] =
        s_pv[0][t] + s_pv[1][t] + s_pv[2][t] + s_pv[3][t];
}

// ----------------------------------------------------- K3: LayerNorm in-place
__global__ __launch_bounds__(256) void ln_kernel(float* __restrict__ out,
                                                 const float* __restrict__ gamma,
                                                 const float* __restrict__ beta) {
    const int row = blockIdx.x;   // B*S = 4096
    float* p = out + (size_t)row * DD;
    const int t = threadIdx.x;
    float x[4];
#pragma unroll
    for (int i = 0; i < 4; i++) x[i] = p[t + 256 * i];
    float sum = x[0] + x[1] + x[2] + x[3];
    __shared__ float red[4];
    const int lane = t & 63, wv = t >> 6;
    for (int off = 32; off; off >>= 1) sum += __shfl_down(sum, off, 64);
    if (lane == 0) red[wv] = sum;
    __syncthreads();
    float mean = (red[0] + red[1] + red[2] + red[3]) * (1.f / DD);
    __syncthreads();
    float vs = 0.f;
#pragma unroll
    for (int i = 0; i < 4; i++) { float d = x[i] - mean; vs += d * d; }
    for (int off = 32; off; off >>= 1) vs += __shfl_down(vs, off, 64);
    if (lane == 0) red[wv] = vs;
    __syncthreads();
    float var = (red[0] + red[1] + red[2] + red[3]) * (1.f / DD);
    float inv = rsqrtf(var + 1e-5f);
#pragma unroll
    for (int i = 0; i < 4; i++) {
        int c = t + 256 * i;
        p[c] = (x[i] - mean) * inv * gamma[c] + beta[c];
    }
}

extern "C" void kernel_launch(void* const* d_in, const int* in_sizes, int n_in,
                              void* d_out, int out_size, void* d_ws, size_t ws_size,
                              hipStream_t stream) {
    const float* q = (const float*)d_in[0];
    const float* k = (const float*)d_in[1];
    const float* v = (const float*)d_in[2];
    const float* aw = (const float*)d_in[3];
    const float* gamma = (const float*)d_in[4];
    const float* beta = (const float*)d_in[5];
    float* out = (float*)d_out;

    int* idx_ws = (int*)d_ws;                                        // 4 MB
    float* ws_m = (float*)((char*)d_ws + ((size_t)4 << 20));         // 512 KB
    float* ws_l = ws_m + (size_t)4 * ROWS;                           // 512 KB
    _Float16* q16 = (_Float16*)((char*)d_ws + ((size_t)8 << 20));    // 8 MB
    _Float16* k16 = q16 + (size_t)BH * SS * HD;                      // 8 MB
    _Float16* v16 = k16 + (size_t)BH * SS * HD;                      // 8 MB

    hipLaunchKernelGGL(cvt_kernel, dim3(BB * SS), dim3(256), 0, stream, q, k, v, q16, k16, v16);
    hipLaunchKernelGGL(topk_kernel, dim3(ROWS), dim3(256), 0, stream, aw, idx_ws);
    hipLaunchKernelGGL(stats_kernel, dim3(1024), dim3(256), 0, stream, q16, k16, ws_m, ws_l);
    hipLaunchKernelGGL(attnout_kernel, dim3(ROWS), dim3(128), 0, stream, q, k, v16, idx_ws, ws_m, ws_l, out);
    hipLaunchKernelGGL(ln_kernel, dim3(BB * SS), dim3(256), 0, stream, out, gamma, beta);
}